// Round 3
// baseline (201.490 us; speedup 1.0000x reference)
//
#include <hip/hip_runtime.h>
#include <cstdint>
#include <cstddef>

#define D_     256
#define TWO_D  512
#define R_     16
#define N0_    8192
#define L_     6
#define NL_    8192
#define B_     512
#define TOTAL_ (N0_ + L_*NL_)

#define MT      32          // nodes (M) per block -> 256 blocks
#define XPITCH  520         // bf16 elems per X row (512 + 8 pad)
#define HPITCH  264         // bf16 elems per H row (256 + 8 pad)
#define OPITCH  264         // out-stage pitch (reuses X buffer)
#define NBLK    256         // == CU count; 1 block/CU => co-resident

using short8  = __attribute__((ext_vector_type(8))) short;     // 8 bf16
using f32x4   = __attribute__((ext_vector_type(4))) float;     // 4 fp32 acc
using uint32x4 = __attribute__((ext_vector_type(4))) unsigned; // 16B chunk
using uint32x2 = __attribute__((ext_vector_type(2))) unsigned; // 8B chunk

__device__ __forceinline__ unsigned short f2bf(float f) {
    union { float f; unsigned u; } v; v.f = f;
    unsigned u = v.u;
    return (unsigned short)((u + 0x7FFFu + ((u >> 16) & 1u)) >> 16);  // RNE
}
__device__ __forceinline__ float bf2f(unsigned short h) {
    union { unsigned u; float f; } v; v.u = ((unsigned)h) << 16;
    return v.f;
}
__device__ __forceinline__ float softplus_f(float x) {
    return fmaxf(x, 0.0f) + log1pf(expf(-fabsf(x)));
}

__device__ __forceinline__ void eval_accum(float x, float pos, float neg, float pw,
                                           float& loss, float& posTot, float& negTot,
                                           float& posOK, float& negOK) {
    float tot = pos + neg;
    if (tot > 0.0f) {
        float tgt = pos / fmaxf(tot, 1e-9f);
        loss += tot * (pw * tgt * softplus_f(-x) + (1.0f - tgt) * softplus_f(x));
        posTot += pos; negTot += neg;
        if (x >= 0.0f) posOK += pos; else negOK += neg;
    }
}

// ---- L3-coherent (sc0 sc1) access path for storeb: stores write through to
// the coherence point, loads read from it bypassing (and not polluting)
// L1/L2. With ALL cross-block data on this path, grid barriers need NO cache
// maintenance (no wbL2 / no invL2) — just vmcnt-drain + counter.
__device__ __forceinline__ void gload16_sc(uint32x4& d, const void* p) {
    asm volatile("global_load_dwordx4 %0, %1, off sc0 sc1"
                 : "=v"(d) : "v"(p) : "memory");
}
__device__ __forceinline__ void gstore16_sc(void* p, uint32x4 d) {
    asm volatile("global_store_dwordx4 %0, %1, off sc0 sc1"
                 :: "v"(p), "v"(d) : "memory");
}
__device__ __forceinline__ void gstore8_sc(void* p, uint32x2 d) {
    asm volatile("global_store_dwordx2 %0, %1, off sc0 sc1"
                 :: "v"(p), "v"(d) : "memory");
}
// drain all outstanding vmem (stores reached L3, loads landed). sched_barrier
// keeps the compiler from hoisting register uses above the wait (rule #18).
#define WAIT_VM0() do { asm volatile("s_waitcnt vmcnt(0)" ::: "memory"); \
                        __builtin_amdgcn_sched_barrier(0); } while (0)

// Fence-free grid barrier (caller must WAIT_VM0 first; sc1 data path makes
// cache maintenance unnecessary). Relaxed spin; bounded as a no-hang valve.
__device__ __forceinline__ void grid_barrier_nf(unsigned* bar, int phase) {
    __syncthreads();
    if (threadIdx.x == 0) {
        __hip_atomic_fetch_add(&bar[phase], 1u, __ATOMIC_RELAXED,
                               __HIP_MEMORY_SCOPE_AGENT);
        unsigned guard = 0;
        while (__hip_atomic_load(&bar[phase], __ATOMIC_RELAXED,
                                 __HIP_MEMORY_SCOPE_AGENT) < (unsigned)NBLK) {
            __builtin_amdgcn_s_sleep(2);
            if (++guard > (1u << 24)) break;   // safety valve vs. deadlock
        }
    }
    __syncthreads();
}

// ---------------------------------------------------------------- prep ----
// W [r][K][256] fp32 -> fragment image [r][ks][q][n][8] bf16. One kernel for
// both W1 (blocks 0..255) and W2 (blocks 256..383). Also zeroes accum[0..7]
// and the 8 grid-barrier counters (accum[8..15]).
__global__ void wimg_k(const float* __restrict__ W1in,
                       const float* __restrict__ W2in,
                       unsigned short* __restrict__ img1,
                       unsigned short* __restrict__ img2,
                       float* __restrict__ accum) {
    if (blockIdx.x == 0 && threadIdx.x < 16) accum[threadIdx.x] = 0.0f;
    int b = blockIdx.x;
    const float* W; unsigned short* img; int KS, rb;
    if (b < R_ * 16) { W = W1in; img = img1; KS = 16; rb = b; }
    else             { W = W2in; img = img2; KS = 8;  rb = b - R_ * 16; }
    int r  = rb / KS;
    int ks = rb - r * KS;
    const float* src = W + (size_t)r * KS * 32 * 256;
    #pragma unroll
    for (int it = 0; it < 4; ++it) {
        int item = it * 256 + threadIdx.x;      // 0..1023 = 4q x 256n
        int q = item >> 8, n = item & 255;
        short8 v;
        #pragma unroll
        for (int j = 0; j < 8; ++j)
            v[j] = (short)f2bf(src[(size_t)(ks * 32 + q * 8 + j) * 256 + n]);
        *(short8*)(img + ((((size_t)r * KS + ks) * 4 + q) * 256 + n) * 8) = v;
    }
}

// ---------------------------------------------------------------- fused ----
// v3 vs v2:
//  * storeb traffic entirely on the sc0/sc1 (L3-coherent) path -> fence-free
//    grid barriers (no per-layer L2 writeback/invalidate).
//  * gather prefetch: parents already visible (id < N0+l*NL) are loaded into
//    registers BEFORE the barrier -> latency hides under barrier skew.
//  * par loads for layer l+1 issued at the start of layer l; b1/b2 bias
//    loads hoisted out of the layer loop.
__global__ __launch_bounds__(512, 2)
void fused_k(unsigned short* __restrict__ storeb,
             const int* __restrict__ thax,
             const float* __restrict__ table,
             const int* __restrict__ par_all,           // [L][NL][2]
             const unsigned short* __restrict__ w1img,  // [R][16][4][256][8]
             const unsigned short* __restrict__ w2img,  // [R][8][4][256][8]
             const float* __restrict__ b1v,
             const float* __restrict__ b2v,
             const float* __restrict__ eval_w,
             const float* __restrict__ eval_b,
             const float* __restrict__ pos_vals,
             const float* __restrict__ neg_vals,
             const float* __restrict__ pos_weight,
             float* __restrict__ accum,
             unsigned* __restrict__ bar,
             float* __restrict__ out) {
    __shared__ unsigned short X[MT * XPITCH];   // 33280 B (also out-stage)
    __shared__ unsigned short H[MT * HPITCH];   // 16896 B
    __shared__ float shred[5];

    const int bid  = blockIdx.x;
    const int tid  = threadIdx.x;
    const int w    = tid >> 6;        // wave 0..7 -> n-slice base w*32
    const int lane = tid & 63;
    const int q    = lane >> 4;
    const int ml   = lane & 15;
    const int nb   = w * 32;

    const int r  = (bid & 7) | (((bid >> 3) & 1) << 3);   // XCD-local rule
    const int mt = bid >> 4;
    const int nodeInLayer0 = r * B_ + mt * MT;

    // --- full W register file: W1 ks=0..15 -> slots 0..31, W2 -> 32..47.
    // Normal cached loads: 16 blocks per XCD share a rule image via L2.
    const unsigned short* w1r = w1img + (size_t)r * 16 * 4 * 256 * 8;
    const unsigned short* w2r = w2img + (size_t)r * 8 * 4 * 256 * 8;
    const size_t fb = (size_t)(q * 256 + nb + ml) * 8;   // per-lane frag base
    short8 breg[48];
    #pragma unroll
    for (int p = 0; p < 16; ++p) {
        breg[p * 2 + 0] = *(const short8*)(&w1r[fb + (size_t)p * 8192]);
        breg[p * 2 + 1] = *(const short8*)(&w1r[fb + (size_t)p * 8192 + 128]);
    }
    #pragma unroll
    for (int p = 0; p < 8; ++p) {
        breg[32 + p * 2 + 0] = *(const short8*)(&w2r[fb + (size_t)p * 8192]);
        breg[32 + p * 2 + 1] = *(const short8*)(&w2r[fb + (size_t)p * 8192 + 128]);
    }

    // layer-invariant scalars hoisted out of the loop
    const float ew0 = eval_w[lane * 4 + 0], ew1 = eval_w[lane * 4 + 1];
    const float ew2 = eval_w[lane * 4 + 2], ew3 = eval_w[lane * 4 + 3];
    const float eb = eval_b[0], pw = pos_weight[0];
    float bias1[2], bias2[2];
    #pragma unroll
    for (int ni = 0; ni < 2; ++ni) {
        bias1[ni] = b1v[r * D_ + nb + ni * 16 + ml];
        bias2[ni] = b2v[r * D_ + nb + ni * 16 + ml];
    }
    float loss = 0.f, posTot = 0.f, negTot = 0.f, posOK = 0.f, negOK = 0.f;

    // parent indices for layer 0 (par is read-only input: load any time)
    int pidx[4];
    #pragma unroll
    for (int it = 0; it < 4; ++it) {
        int c = it * 512 + tid;
        pidx[it] = par_all[(nodeInLayer0 + (c >> 6)) * 2 + ((c & 63) >> 5)];
    }

    // ---- phase 0: init gather + eval; storeb writes on the sc1 path.
    {
        int base = bid * MT;
        #pragma unroll
        for (int rr = 0; rr < 4; ++rr) {
            int row = base + w * 4 + rr;
            int t = thax[row];
            float4 v = *(const float4*)(table + (size_t)t * D_ + lane * 4);
            unsigned short bx = f2bf(v.x), by = f2bf(v.y);
            unsigned short bz = f2bf(v.z), bw = f2bf(v.w);
            uint32x2 o2; o2[0] = (unsigned)bx | ((unsigned)by << 16);
            o2[1] = (unsigned)bz | ((unsigned)bw << 16);
            gstore8_sc((char*)storeb + (((size_t)row) << 9) + (size_t)lane * 8, o2);
            float s = bf2f(bx)*ew0 + bf2f(by)*ew1 + bf2f(bz)*ew2 + bf2f(bw)*ew3;
            #pragma unroll
            for (int off = 32; off > 0; off >>= 1) s += __shfl_down(s, off);
            if (lane == 0)
                eval_accum(s + eb, pos_vals[row], neg_vals[row], pw,
                           loss, posTot, negTot, posOK, negOK);
        }
    }
    WAIT_VM0();
    grid_barrier_nf(bar, 0);

    uint32x4 pf[4];            // gather chunks (live across the barrier)
    const int c16 = tid & 31;  // 16B chunk index within a 512B row

    for (int l = 0; l < L_; ++l) {
        // ---- finish the gather: load parents NOT prefetched pre-barrier
        int prevLimit = (l == 0) ? 0 : (N0_ + (l - 1) * NL_);
        #pragma unroll
        for (int it = 0; it < 4; ++it) {
            if (pidx[it] >= prevLimit)
                gload16_sc(pf[it], (const char*)storeb +
                           ((size_t)(unsigned)pidx[it] << 9) + (c16 << 4));
        }
        // par loads for the NEXT layer (independent; hides under this layer)
        int pidxN[4];
        if (l < L_ - 1) {
            const int* parN = par_all + (size_t)(l + 1) * NL_ * 2;
            #pragma unroll
            for (int it = 0; it < 4; ++it) {
                int c = it * 512 + tid;
                pidxN[it] = parN[(nodeInLayer0 + (c >> 6)) * 2 + ((c & 63) >> 5)];
            }
        }
        WAIT_VM0();
        #pragma unroll
        for (int it = 0; it < 4; ++it) {
            int c   = it * 512 + tid;
            int m   = c >> 6;
            int j   = (c & 63) >> 5;
            *((uint32x4*)(&X[m * XPITCH + j * D_ + c16 * 8])) = pf[it];
        }
        __syncthreads();

        // ---- GEMM1: [32 x 512] @ [512 x 256] -> H, relu(.+b1). B in regs.
        f32x4 acc[2][2] = {};
        #pragma unroll
        for (int ks = 0; ks < 16; ++ks) {
            int k0 = ks * 32 + q * 8;
            short8 a0 = *(const short8*)(&X[ml * XPITCH + k0]);
            short8 a1 = *(const short8*)(&X[(16 + ml) * XPITCH + k0]);
            acc[0][0] = __builtin_amdgcn_mfma_f32_16x16x32_bf16(a0, breg[ks*2+0], acc[0][0], 0, 0, 0);
            acc[1][0] = __builtin_amdgcn_mfma_f32_16x16x32_bf16(a1, breg[ks*2+0], acc[1][0], 0, 0, 0);
            acc[0][1] = __builtin_amdgcn_mfma_f32_16x16x32_bf16(a0, breg[ks*2+1], acc[0][1], 0, 0, 0);
            acc[1][1] = __builtin_amdgcn_mfma_f32_16x16x32_bf16(a1, breg[ks*2+1], acc[1][1], 0, 0, 0);
        }
        #pragma unroll
        for (int ni = 0; ni < 2; ++ni) {
            int n = nb + ni * 16 + ml;
            #pragma unroll
            for (int mi = 0; mi < 2; ++mi)
                #pragma unroll
                for (int v = 0; v < 4; ++v) {
                    int row = mi * 16 + q * 4 + v;   // C/D: row = quad*4+reg
                    float x = acc[mi][ni][v] + bias1[ni];
                    H[row * HPITCH + n] = f2bf(x > 0.0f ? x : 0.0f);
                }
        }
        __syncthreads();

        // ---- GEMM2: [32 x 256] @ [256 x 256] (+b2). B in regs (slots 32+).
        f32x4 acc2[2][2] = {};
        #pragma unroll
        for (int ks = 0; ks < 8; ++ks) {
            int k0 = ks * 32 + q * 8;
            short8 a0 = *(const short8*)(&H[ml * HPITCH + k0]);
            short8 a1 = *(const short8*)(&H[(16 + ml) * HPITCH + k0]);
            acc2[0][0] = __builtin_amdgcn_mfma_f32_16x16x32_bf16(a0, breg[32+ks*2+0], acc2[0][0], 0, 0, 0);
            acc2[1][0] = __builtin_amdgcn_mfma_f32_16x16x32_bf16(a1, breg[32+ks*2+0], acc2[1][0], 0, 0, 0);
            acc2[0][1] = __builtin_amdgcn_mfma_f32_16x16x32_bf16(a0, breg[32+ks*2+1], acc2[0][1], 0, 0, 0);
            acc2[1][1] = __builtin_amdgcn_mfma_f32_16x16x32_bf16(a1, breg[32+ks*2+1], acc2[1][1], 0, 0, 0);
        }
        // X reads all finished before post-GEMM1 barrier -> reuse X as out-stage
        #pragma unroll
        for (int ni = 0; ni < 2; ++ni) {
            int n = nb + ni * 16 + ml;
            #pragma unroll
            for (int mi = 0; mi < 2; ++mi)
                #pragma unroll
                for (int v = 0; v < 4; ++v) {
                    int row = mi * 16 + q * 4 + v;
                    float x = acc2[mi][ni][v] + bias2[ni];
                    X[row * OPITCH + n] = f2bf(x);
                }
        }
        __syncthreads();

        size_t outBase = (size_t)(N0_ + l * NL_ + nodeInLayer0);
        // coalesced sc1 store (skip last layer: nobody gathers from it)
        if (l != L_ - 1) {
            #pragma unroll
            for (int it = 0; it < 2; ++it) {
                int c   = it * 512 + tid;       // 0..1023 = 32 rows x 32 chunks
                int m   = c >> 5;
                int cc  = c & 31;
                uint32x4 v = *((const uint32x4*)(&X[m * OPITCH]) + cc);
                gstore16_sc((char*)storeb + ((outBase + m) << 9) + (cc << 4), v);
            }
        }
        // fused eval of this tile from the LDS out-stage (overlaps stores)
        #pragma unroll
        for (int rr = 0; rr < 4; ++rr) {
            int row = w * 4 + rr;
            ushort4 vv = *(const ushort4*)(&X[row * OPITCH + lane * 4]);
            float s = bf2f(vv.x)*ew0 + bf2f(vv.y)*ew1 + bf2f(vv.z)*ew2 + bf2f(vv.w)*ew3;
            #pragma unroll
            for (int off = 32; off > 0; off >>= 1) s += __shfl_down(s, off);
            if (lane == 0)
                eval_accum(s + eb, pos_vals[outBase + row], neg_vals[outBase + row], pw,
                           loss, posTot, negTot, posOK, negOK);
        }
        if (l != L_ - 1) {
            WAIT_VM0();   // stores at L3 before arrive
            // prefetch for layer l+1: rows < N0+l*NL are already visible
            // (guaranteed by the PREVIOUS barrier) -> load them pre-barrier.
            int limit = N0_ + l * NL_;
            #pragma unroll
            for (int it = 0; it < 4; ++it) {
                if (pidxN[it] < limit)
                    gload16_sc(pf[it], (const char*)storeb +
                               ((size_t)(unsigned)pidxN[it] << 9) + (c16 << 4));
            }
            grid_barrier_nf(bar, 1 + l);
            #pragma unroll
            for (int it = 0; it < 4; ++it) pidx[it] = pidxN[it];
        }
    }

    // ---- final reduce: block-local via LDS, one device-atomic set per block
    if (tid < 5) shred[tid] = 0.0f;
    __syncthreads();
    if (lane == 0) {
        atomicAdd(&shred[0], loss);
        atomicAdd(&shred[1], posTot);
        atomicAdd(&shred[2], negTot);
        atomicAdd(&shred[3], posOK);
        atomicAdd(&shred[4], negOK);
    }
    __syncthreads();
    if (tid < 5) atomicAdd(&accum[tid], shred[tid]);   // device-scope, at L3
    // last barrier: arrive (no spin except block 0), then block 0 finalizes.
    if (tid == 0) {
        WAIT_VM0();   // accum atomics performed before arrive
        __hip_atomic_fetch_add(&bar[6], 1u, __ATOMIC_RELAXED,
                               __HIP_MEMORY_SCOPE_AGENT);
        if (bid == 0) {
            unsigned guard = 0;
            while (__hip_atomic_load(&bar[6], __ATOMIC_RELAXED,
                                     __HIP_MEMORY_SCOPE_AGENT) < (unsigned)NBLK) {
                __builtin_amdgcn_s_sleep(2);
                if (++guard > (1u << 24)) break;
            }
            float vloss   = __hip_atomic_load(&accum[0], __ATOMIC_RELAXED, __HIP_MEMORY_SCOPE_AGENT);
            float vposTot = __hip_atomic_load(&accum[1], __ATOMIC_RELAXED, __HIP_MEMORY_SCOPE_AGENT);
            float vnegTot = __hip_atomic_load(&accum[2], __ATOMIC_RELAXED, __HIP_MEMORY_SCOPE_AGENT);
            float vposOK  = __hip_atomic_load(&accum[3], __ATOMIC_RELAXED, __HIP_MEMORY_SCOPE_AGENT);
            float vnegOK  = __hip_atomic_load(&accum[4], __ATOMIC_RELAXED, __HIP_MEMORY_SCOPE_AGENT);
            out[0] = vloss;
            out[1] = (vposTot > 0.0f) ? vposOK / fmaxf(vposTot, 1e-9f) : 1.0f;
            out[2] = (vnegTot > 0.0f) ? vnegOK / fmaxf(vnegTot, 1e-9f) : 1.0f;
        }
    }
}

// ---------------------------------------------------------------- launch ---
extern "C" void kernel_launch(void* const* d_in, const int* in_sizes, int n_in,
                              void* d_out, int out_size, void* d_ws, size_t ws_size,
                              hipStream_t stream) {
    const int*   thax       = (const int*)  d_in[0];
    const int*   par        = (const int*)  d_in[1];
    const float* pos_vals   = (const float*)d_in[2];
    const float* neg_vals   = (const float*)d_in[3];
    const float* init_table = (const float*)d_in[4];
    const float* W1         = (const float*)d_in[5];
    const float* b1         = (const float*)d_in[6];
    const float* W2         = (const float*)d_in[7];
    const float* b2         = (const float*)d_in[8];
    const float* eval_w     = (const float*)d_in[9];
    const float* eval_b     = (const float*)d_in[10];
    const float* pos_weight = (const float*)d_in[11];
    float* out = (float*)d_out;

    char* ws = (char*)d_ws;
    unsigned short* w1img  = (unsigned short*)(ws);                            // 4 MB
    unsigned short* w2img  = (unsigned short*)(ws + (size_t)4  * 1024 * 1024); // 2 MB
    unsigned short* storeb = (unsigned short*)(ws + (size_t)6  * 1024 * 1024); // 28 MB
    float*          accum  = (float*)(ws + (size_t)6 * 1024 * 1024 +
                                      (size_t)TOTAL_ * D_ * 2);
    unsigned*       bar    = (unsigned*)(accum + 8);   // 8 barrier counters

    hipLaunchKernelGGL(wimg_k, dim3(R_ * 16 + R_ * 8), dim3(256), 0, stream,
                       W1, W2, w1img, w2img, accum);
    hipLaunchKernelGGL(fused_k, dim3(NBLK), dim3(512), 0, stream,
                       storeb, thax, init_table, par, w1img, w2img, b1, b2,
                       eval_w, eval_b, pos_vals, neg_vals, pos_weight,
                       accum, bar, out);
}

// Round 4
// 200.088 us; speedup vs baseline: 1.0070x; 1.0070x over previous
//
#include <hip/hip_runtime.h>
#include <cstdint>
#include <cstddef>

#define D_     256
#define TWO_D  512
#define R_     16
#define N0_    8192
#define L_     6
#define NL_    8192
#define B_     512
#define TOTAL_ (N0_ + L_*NL_)

#define MT      32          // nodes (M) per block -> 256 blocks
#define XPITCH  520         // bf16 elems per X row (512 + 8 pad)
#define HPITCH  264         // bf16 elems per H row (256 + 8 pad)
#define OPITCH  264         // out-stage pitch (reuses X buffer)
#define NBLK    256         // == CU count; 1 block/CU => co-resident

using short8 = __attribute__((ext_vector_type(8))) short;   // 8 bf16 (4 VGPRs)
using f32x4  = __attribute__((ext_vector_type(4))) float;   // 4 fp32 acc

__device__ __forceinline__ unsigned short f2bf(float f) {
    union { float f; unsigned u; } v; v.f = f;
    unsigned u = v.u;
    return (unsigned short)((u + 0x7FFFu + ((u >> 16) & 1u)) >> 16);  // RNE
}
__device__ __forceinline__ float bf2f(unsigned short h) {
    union { unsigned u; float f; } v; v.u = ((unsigned)h) << 16;
    return v.f;
}
__device__ __forceinline__ float softplus_f(float x) {
    return fmaxf(x, 0.0f) + log1pf(expf(-fabsf(x)));
}

__device__ __forceinline__ void eval_accum(float x, float pos, float neg, float pw,
                                           float& loss, float& posTot, float& negTot,
                                           float& posOK, float& negOK) {
    float tot = pos + neg;
    if (tot > 0.0f) {
        float tgt = pos / fmaxf(tot, 1e-9f);
        loss += tot * (pw * tgt * softplus_f(-x) + (1.0f - tgt) * softplus_f(x));
        posTot += pos; negTot += neg;
        if (x >= 0.0f) posOK += pos; else negOK += neg;
    }
}

// Device-scope grid barrier (round-2 proven form): RELAXED spin, exactly one
// release fence (wbL2) before arrive and one acquire fence (invL2) on exit.
__device__ __forceinline__ void grid_barrier(unsigned* bar, int phase) {
    __syncthreads();
    if (threadIdx.x == 0) {
        __builtin_amdgcn_fence(__ATOMIC_RELEASE, "agent");
        __hip_atomic_fetch_add(&bar[phase], 1u, __ATOMIC_RELAXED,
                               __HIP_MEMORY_SCOPE_AGENT);
        unsigned guard = 0;
        while (__hip_atomic_load(&bar[phase], __ATOMIC_RELAXED,
                                 __HIP_MEMORY_SCOPE_AGENT) < (unsigned)NBLK) {
            __builtin_amdgcn_s_sleep(2);
            if (++guard > (1u << 24)) break;   // safety valve vs. deadlock
        }
        __builtin_amdgcn_fence(__ATOMIC_ACQUIRE, "agent");
    }
    __syncthreads();
}

// ---------------------------------------------------------------- prep ----
// W [r][K][256] fp32 -> fragment image [r][ks][q][n][8] bf16. One kernel for
// both W1 (blocks 0..255) and W2 (blocks 256..383). Also zeroes accum[0..7]
// and the 8 grid-barrier counters (accum[8..15]).
__global__ void wimg_k(const float* __restrict__ W1in,
                       const float* __restrict__ W2in,
                       unsigned short* __restrict__ img1,
                       unsigned short* __restrict__ img2,
                       float* __restrict__ accum) {
    if (blockIdx.x == 0 && threadIdx.x < 16) accum[threadIdx.x] = 0.0f;
    int b = blockIdx.x;
    const float* W; unsigned short* img; int KS, rb;
    if (b < R_ * 16) { W = W1in; img = img1; KS = 16; rb = b; }
    else             { W = W2in; img = img2; KS = 8;  rb = b - R_ * 16; }
    int r  = rb / KS;
    int ks = rb - r * KS;
    const float* src = W + (size_t)r * KS * 32 * 256;
    #pragma unroll
    for (int it = 0; it < 4; ++it) {
        int item = it * 256 + threadIdx.x;      // 0..1023 = 4q x 256n
        int q = item >> 8, n = item & 255;
        short8 v;
        #pragma unroll
        for (int j = 0; j < 8; ++j)
            v[j] = (short)f2bf(src[(size_t)(ks * 32 + q * 8 + j) * 256 + n]);
        *(short8*)(img + ((((size_t)r * KS + ks) * 4 + q) * 256 + n) * 8) = v;
    }
}

// ---------------------------------------------------------------- fused ----
// v4 = round-2 structure (fenced barrier, normal cached storeb path) with
// TRUE register residency of all 48 W fragments:
//  * waves_per_eu(2,2): tells the allocator occupancy beyond 2 waves/EU is
//    useless -> VGPR budget 256 (round 2/3 sat at 128 and silently
//    REMATERIALIZED breg from global every layer: the hidden weight
//    re-stream this version eliminates).
//  * opaque empty-asm pins each fragment: uses reference the asm result,
//    which the compiler cannot rematerialize from memory.
__global__ __launch_bounds__(512)
__attribute__((amdgpu_waves_per_eu(2, 2)))
void fused_k(unsigned short* __restrict__ storeb,
             const int* __restrict__ thax,
             const float* __restrict__ table,
             const int* __restrict__ par_all,           // [L][NL][2]
             const unsigned short* __restrict__ w1img,  // [R][16][4][256][8]
             const unsigned short* __restrict__ w2img,  // [R][8][4][256][8]
             const float* __restrict__ b1v,
             const float* __restrict__ b2v,
             const float* __restrict__ eval_w,
             const float* __restrict__ eval_b,
             const float* __restrict__ pos_vals,
             const float* __restrict__ neg_vals,
             const float* __restrict__ pos_weight,
             float* __restrict__ accum,
             unsigned* __restrict__ bar,
             float* __restrict__ out) {
    __shared__ unsigned short X[MT * XPITCH];   // 33280 B (also out-stage)
    __shared__ unsigned short H[MT * HPITCH];   // 16896 B
    __shared__ float shred[5];

    const int bid  = blockIdx.x;
    const int tid  = threadIdx.x;
    const int w    = tid >> 6;        // wave 0..7 -> n-slice base w*32
    const int lane = tid & 63;
    const int q    = lane >> 4;
    const int ml   = lane & 15;
    const int nb   = w * 32;

    const int r  = (bid & 7) | (((bid >> 3) & 1) << 3);   // XCD-local rule
    const int mt = bid >> 4;
    const int nodeInLayer0 = r * B_ + mt * MT;

    // --- full W register file: W1 ks=0..15 -> slots 0..31, W2 -> 32..47.
    const unsigned short* w1r = w1img + (size_t)r * 16 * 4 * 256 * 8;
    const unsigned short* w2r = w2img + (size_t)r * 8 * 4 * 256 * 8;
    const size_t fb = (size_t)(q * 256 + nb + ml) * 8;   // per-lane frag base
    short8 breg[48];
    #pragma unroll
    for (int p = 0; p < 16; ++p) {
        breg[p * 2 + 0] = *(const short8*)(&w1r[fb + (size_t)p * 8192]);
        breg[p * 2 + 1] = *(const short8*)(&w1r[fb + (size_t)p * 8192 + 128]);
    }
    #pragma unroll
    for (int p = 0; p < 8; ++p) {
        breg[32 + p * 2 + 0] = *(const short8*)(&w2r[fb + (size_t)p * 8192]);
        breg[32 + p * 2 + 1] = *(const short8*)(&w2r[fb + (size_t)p * 8192 + 128]);
    }

    // layer-invariant scalars hoisted out of the loop
    const float ew0 = eval_w[lane * 4 + 0], ew1 = eval_w[lane * 4 + 1];
    const float ew2 = eval_w[lane * 4 + 2], ew3 = eval_w[lane * 4 + 3];
    const float eb = eval_b[0], pw = pos_weight[0];
    float bias1[2], bias2[2];
    #pragma unroll
    for (int ni = 0; ni < 2; ++ni) {
        bias1[ni] = b1v[r * D_ + nb + ni * 16 + ml];
        bias2[ni] = b2v[r * D_ + nb + ni * 16 + ml];
    }
    float loss = 0.f, posTot = 0.f, negTot = 0.f, posOK = 0.f, negOK = 0.f;

    // ---- phase 0: init gather + eval (overlaps the weight preload above).
    {
        int base = bid * MT;
        #pragma unroll
        for (int rr = 0; rr < 4; ++rr) {
            int row = base + w * 4 + rr;
            int t = thax[row];
            float4 v = *(const float4*)(table + (size_t)t * D_ + lane * 4);
            ushort4 o;
            o.x = f2bf(v.x); o.y = f2bf(v.y); o.z = f2bf(v.z); o.w = f2bf(v.w);
            *(ushort4*)(storeb + (size_t)row * D_ + lane * 4) = o;
            float s = bf2f(o.x)*ew0 + bf2f(o.y)*ew1 + bf2f(o.z)*ew2 + bf2f(o.w)*ew3;
            #pragma unroll
            for (int off = 32; off > 0; off >>= 1) s += __shfl_down(s, off);
            if (lane == 0)
                eval_accum(s + eb, pos_vals[row], neg_vals[row], pw,
                           loss, posTot, negTot, posOK, negOK);
        }
    }

    // pin the weight register file: from here on every use references the
    // asm result -> cannot be rematerialized by re-loading from global.
    #pragma unroll
    for (int p = 0; p < 48; ++p)
        asm volatile("" : "+v"(breg[p]));

    grid_barrier(bar, 0);

    for (int l = 0; l < L_; ++l) {
        const int* par = par_all + (size_t)l * NL_ * 2;

        // gather parents -> X: 32 rows x 2 parents x 32 chunks, 4/thread
        int pidx[4];
        #pragma unroll
        for (int it = 0; it < 4; ++it) {
            int c = it * 512 + tid;
            pidx[it] = par[(nodeInLayer0 + (c >> 6)) * 2 + ((c & 63) >> 5)];
        }
        #pragma unroll
        for (int it = 0; it < 4; ++it) {
            int c   = it * 512 + tid;
            int m   = c >> 6;
            int rem = c & 63;
            int j   = rem >> 5;
            int c16 = rem & 31;
            uint4 v = *((const uint4*)(storeb + (size_t)pidx[it] * D_) + c16);
            *((uint4*)(&X[m * XPITCH + j * D_ + c16 * 8])) = v;
        }
        __syncthreads();

        // ---- GEMM1: [32 x 512] @ [512 x 256] -> H, relu(.+b1). B in regs.
        f32x4 acc[2][2] = {};
        #pragma unroll
        for (int ks = 0; ks < 16; ++ks) {
            int k0 = ks * 32 + q * 8;
            short8 a0 = *(const short8*)(&X[ml * XPITCH + k0]);
            short8 a1 = *(const short8*)(&X[(16 + ml) * XPITCH + k0]);
            acc[0][0] = __builtin_amdgcn_mfma_f32_16x16x32_bf16(a0, breg[ks*2+0], acc[0][0], 0, 0, 0);
            acc[1][0] = __builtin_amdgcn_mfma_f32_16x16x32_bf16(a1, breg[ks*2+0], acc[1][0], 0, 0, 0);
            acc[0][1] = __builtin_amdgcn_mfma_f32_16x16x32_bf16(a0, breg[ks*2+1], acc[0][1], 0, 0, 0);
            acc[1][1] = __builtin_amdgcn_mfma_f32_16x16x32_bf16(a1, breg[ks*2+1], acc[1][1], 0, 0, 0);
        }
        #pragma unroll
        for (int ni = 0; ni < 2; ++ni) {
            int n = nb + ni * 16 + ml;
            #pragma unroll
            for (int mi = 0; mi < 2; ++mi)
                #pragma unroll
                for (int v = 0; v < 4; ++v) {
                    int row = mi * 16 + q * 4 + v;   // C/D: row = quad*4+reg
                    float x = acc[mi][ni][v] + bias1[ni];
                    H[row * HPITCH + n] = f2bf(x > 0.0f ? x : 0.0f);
                }
        }
        __syncthreads();

        // ---- GEMM2: [32 x 256] @ [256 x 256] (+b2). B in regs (slots 32+).
        f32x4 acc2[2][2] = {};
        #pragma unroll
        for (int ks = 0; ks < 8; ++ks) {
            int k0 = ks * 32 + q * 8;
            short8 a0 = *(const short8*)(&H[ml * HPITCH + k0]);
            short8 a1 = *(const short8*)(&H[(16 + ml) * HPITCH + k0]);
            acc2[0][0] = __builtin_amdgcn_mfma_f32_16x16x32_bf16(a0, breg[32+ks*2+0], acc2[0][0], 0, 0, 0);
            acc2[1][0] = __builtin_amdgcn_mfma_f32_16x16x32_bf16(a1, breg[32+ks*2+0], acc2[1][0], 0, 0, 0);
            acc2[0][1] = __builtin_amdgcn_mfma_f32_16x16x32_bf16(a0, breg[32+ks*2+1], acc2[0][1], 0, 0, 0);
            acc2[1][1] = __builtin_amdgcn_mfma_f32_16x16x32_bf16(a1, breg[32+ks*2+1], acc2[1][1], 0, 0, 0);
        }
        // X reads all finished before post-GEMM1 barrier -> reuse X as out-stage
        #pragma unroll
        for (int ni = 0; ni < 2; ++ni) {
            int n = nb + ni * 16 + ml;
            #pragma unroll
            for (int mi = 0; mi < 2; ++mi)
                #pragma unroll
                for (int v = 0; v < 4; ++v) {
                    int row = mi * 16 + q * 4 + v;
                    float x = acc2[mi][ni][v] + bias2[ni];
                    X[row * OPITCH + n] = f2bf(x);
                }
        }
        __syncthreads();

        size_t outBase = (size_t)(N0_ + l * NL_ + nodeInLayer0);
        // coalesced store (skip last layer: nobody gathers from it)
        if (l != L_ - 1) {
            #pragma unroll
            for (int it = 0; it < 2; ++it) {
                int c   = it * 512 + tid;       // 0..1023 = 32 rows x 32 chunks
                int m   = c >> 5;
                int c16 = c & 31;
                uint4 v = *((const uint4*)(&X[m * OPITCH]) + c16);
                *((uint4*)(storeb + (outBase + m) * D_) + c16) = v;
            }
        }
        // fused eval of this tile from the LDS out-stage
        #pragma unroll
        for (int rr = 0; rr < 4; ++rr) {
            int row = w * 4 + rr;
            ushort4 vv = *(const ushort4*)(&X[row * OPITCH + lane * 4]);
            float s = bf2f(vv.x)*ew0 + bf2f(vv.y)*ew1 + bf2f(vv.z)*ew2 + bf2f(vv.w)*ew3;
            #pragma unroll
            for (int off = 32; off > 0; off >>= 1) s += __shfl_down(s, off);
            if (lane == 0)
                eval_accum(s + eb, pos_vals[outBase + row], neg_vals[outBase + row], pw,
                           loss, posTot, negTot, posOK, negOK);
        }
        if (l != L_ - 1) grid_barrier(bar, 1 + l);   // phases 1..5
    }

    // ---- final reduce: block-local via LDS, one device-atomic set per block
    if (tid < 5) shred[tid] = 0.0f;
    __syncthreads();
    if (lane == 0) {
        atomicAdd(&shred[0], loss);
        atomicAdd(&shred[1], posTot);
        atomicAdd(&shred[2], negTot);
        atomicAdd(&shred[3], posOK);
        atomicAdd(&shred[4], negOK);
    }
    __syncthreads();
    if (tid < 5) atomicAdd(&accum[tid], shred[tid]);
    __syncthreads();
    // last barrier: blocks != 0 arrive and EXIT (no spin); block 0 waits,
    // then finalizes. accum adds are device-scope atomics (coherence point).
    if (tid == 0) {
        __builtin_amdgcn_fence(__ATOMIC_RELEASE, "agent");
        __hip_atomic_fetch_add(&bar[6], 1u, __ATOMIC_RELAXED,
                               __HIP_MEMORY_SCOPE_AGENT);
        if (bid == 0) {
            unsigned guard = 0;
            while (__hip_atomic_load(&bar[6], __ATOMIC_RELAXED,
                                     __HIP_MEMORY_SCOPE_AGENT) < (unsigned)NBLK) {
                __builtin_amdgcn_s_sleep(2);
                if (++guard > (1u << 24)) break;
            }
            __builtin_amdgcn_fence(__ATOMIC_ACQUIRE, "agent");
            float vloss   = __hip_atomic_load(&accum[0], __ATOMIC_RELAXED, __HIP_MEMORY_SCOPE_AGENT);
            float vposTot = __hip_atomic_load(&accum[1], __ATOMIC_RELAXED, __HIP_MEMORY_SCOPE_AGENT);
            float vnegTot = __hip_atomic_load(&accum[2], __ATOMIC_RELAXED, __HIP_MEMORY_SCOPE_AGENT);
            float vposOK  = __hip_atomic_load(&accum[3], __ATOMIC_RELAXED, __HIP_MEMORY_SCOPE_AGENT);
            float vnegOK  = __hip_atomic_load(&accum[4], __ATOMIC_RELAXED, __HIP_MEMORY_SCOPE_AGENT);
            out[0] = vloss;
            out[1] = (vposTot > 0.0f) ? vposOK / fmaxf(vposTot, 1e-9f) : 1.0f;
            out[2] = (vnegTot > 0.0f) ? vnegOK / fmaxf(vnegTot, 1e-9f) : 1.0f;
        }
    }
}

// ---------------------------------------------------------------- launch ---
extern "C" void kernel_launch(void* const* d_in, const int* in_sizes, int n_in,
                              void* d_out, int out_size, void* d_ws, size_t ws_size,
                              hipStream_t stream) {
    const int*   thax       = (const int*)  d_in[0];
    const int*   par        = (const int*)  d_in[1];
    const float* pos_vals   = (const float*)d_in[2];
    const float* neg_vals   = (const float*)d_in[3];
    const float* init_table = (const float*)d_in[4];
    const float* W1         = (const float*)d_in[5];
    const float* b1         = (const float*)d_in[6];
    const float* W2         = (const float*)d_in[7];
    const float* b2         = (const float*)d_in[8];
    const float* eval_w     = (const float*)d_in[9];
    const float* eval_b     = (const float*)d_in[10];
    const float* pos_weight = (const float*)d_in[11];
    float* out = (float*)d_out;

    char* ws = (char*)d_ws;
    unsigned short* w1img  = (unsigned short*)(ws);                            // 4 MB
    unsigned short* w2img  = (unsigned short*)(ws + (size_t)4  * 1024 * 1024); // 2 MB
    unsigned short* storeb = (unsigned short*)(ws + (size_t)6  * 1024 * 1024); // 28 MB
    float*          accum  = (float*)(ws + (size_t)6 * 1024 * 1024 +
                                      (size_t)TOTAL_ * D_ * 2);
    unsigned*       bar    = (unsigned*)(accum + 8);   // 8 barrier counters

    hipLaunchKernelGGL(wimg_k, dim3(R_ * 16 + R_ * 8), dim3(256), 0, stream,
                       W1, W2, w1img, w2img, accum);
    hipLaunchKernelGGL(fused_k, dim3(NBLK), dim3(512), 0, stream,
                       storeb, thax, init_table, par, w1img, w2img, b1, b2,
                       eval_w, eval_b, pos_vals, neg_vals, pos_weight,
                       accum, bar, out);
}